// Round 13
// baseline (183.928 us; speedup 1.0000x reference)
//
#include <hip/hip_runtime.h>

#define Tn 1024
#define Hn 16
#define Dn 1024
#define DHn 64
// SCALE * log2(e): Q is pre-scaled by this, softmax then uses exp2 directly.
#define QSCALE 0.18033688011112042f

typedef unsigned short u16;
typedef unsigned long long ull;
typedef __bf16 bf16x8 __attribute__((ext_vector_type(8)));
typedef float f32x4 __attribute__((ext_vector_type(4)));

__device__ __forceinline__ u16 f2bf(float f) {
  union { float f; unsigned u; } v; v.f = f;
  return (u16)((v.u + 0x7FFFu + ((v.u >> 16) & 1u)) >> 16);
}
__device__ __forceinline__ float bf2f(u16 s) {
  union { unsigned u; float f; } v; v.u = ((unsigned)s) << 16;
  return v.f;
}
__device__ __forceinline__ f32x4 mfma16(bf16x8 a, bf16x8 b, f32x4 c) {
  return __builtin_amdgcn_mfma_f32_16x16x32_bf16(a, b, c, 0, 0, 0);
}
// async global->LDS, 16B per lane; LDS dst must be wave-uniform (chunk base).
__device__ __forceinline__ void gload16(const u16* g, u16* l) {
  __builtin_amdgcn_global_load_lds(
      (const __attribute__((address_space(1))) void*)g,
      (__attribute__((address_space(3))) void*)l, 16, 0, 0);
}

// ---------------- convert fp32 -> bf16 (linear) ----------------
__global__ void k_convert(const float* __restrict__ src, u16* __restrict__ dst, int n) {
  int i = (blockIdx.x * blockDim.x + threadIdx.x) * 4;
  if (i >= n) return;
  float4 v = *(const float4*)(src + i);
  union { u16 s[4]; uint2 u; } o;
  o.s[0] = f2bf(v.x); o.s[1] = f2bf(v.y); o.s[2] = f2bf(v.z); o.s[3] = f2bf(v.w);
  *(uint2*)(dst + i) = o.u;
}

// ---------------- pack bool mask bytes -> 64-bit words (bit k = mask[base+k]) ----------------
__global__ __launch_bounds__(256) void k_maskpack(const unsigned char* __restrict__ m,
                                                  unsigned long long* __restrict__ mb) {
  int wi = blockIdx.x * 4 + (threadIdx.x >> 6);
  int lane = threadIdx.x & 63;
  unsigned char v = m[((size_t)wi << 6) + lane];
  unsigned long long bal = __ballot(v != 0);
  if (lane == 0) mb[wi] = bal;
}

// ---------------- transpose + convert x4: W[K][N] fp32 -> Wt[N][K] bf16 ----------------
__global__ void k_transpose_convert4(const float* __restrict__ W0, const float* __restrict__ W1,
                                     const float* __restrict__ W2, const float* __restrict__ W3,
                                     u16* __restrict__ T0, u16* __restrict__ T1,
                                     u16* __restrict__ T2, u16* __restrict__ T3) {
  __shared__ float tile[32][33];
  int z = blockIdx.z;
  const float* W = (z == 0) ? W0 : (z == 1) ? W1 : (z == 2) ? W2 : W3;
  u16* Wt = (z == 0) ? T0 : (z == 1) ? T1 : (z == 2) ? T2 : T3;
  int n0 = blockIdx.x * 32, k0 = blockIdx.y * 32;
  int tx = threadIdx.x, ty = threadIdx.y; // (32,8)
  #pragma unroll
  for (int i = 0; i < 4; i++)
    tile[ty + 8*i][tx] = W[(size_t)(k0 + ty + 8*i) * Dn + n0 + tx];
  __syncthreads();
  #pragma unroll
  for (int i = 0; i < 4; i++)
    Wt[(size_t)(n0 + ty + 8*i) * Dn + k0 + tx] = f2bf(tile[tx][ty + 8*i]);
}

// ---------------- merged Q/KV projection GEMM ----------------
// A fp32 reg-staged+converted (padded LDS, 2-way ok); B bf16 via double-buffered
// global_load_lds, LINEAR LDS with PRE-SWIZZLED GLOBAL SOURCE (rule #21):
// lane colseg (l&3) -> (l&3)^((l>>3)&3); read applies the same XOR. Spreads 8
// consecutive rows over all 8 bank-quads -> 2-way (free) instead of 8-way.
__global__ __launch_bounds__(256) void k_proj(const float* __restrict__ x, const float* __restrict__ ctxI,
                                              const u16* __restrict__ WqT, const u16* __restrict__ WkvT,
                                              u16* __restrict__ Qb, u16* __restrict__ Kb, u16* __restrict__ Vb) {
  __shared__ __align__(16) u16 AlP[2][128][40];
  __shared__ __align__(16) u16 BlL[2][128 * 32];
  int bx = blockIdx.x;
  bool isQ = bx < 256;
  int idx = isQ ? bx : bx - 256;
  int m0 = (idx & 31) * 128;
  int n0 = (idx >> 5) * 128;
  const float* A = isQ ? x : ctxI;
  const u16* Bt = isQ ? WqT : WkvT;
  u16* dst0 = isQ ? Qb : Kb;
  float scale = isQ ? QSCALE : 1.0f;
  int tid = threadIdx.x;
  int w = tid >> 6, lane = tid & 63, g = lane >> 4, lr = lane & 15;
  int wr = w >> 1, wc = w & 1;
  f32x4 acc[4][4] = {};
  // A staging (fp32 -> bf16): thread covers rows sr, sr+64, colseg sc*8
  int sr = tid >> 2, sc = tid & 3;
  const float* Ap0 = &A[(size_t)(m0 + sr) * Dn + sc * 8];
  const float* Ap1 = Ap0 + (size_t)64 * Dn;
  // B gload mapping: wave w stages 1KB chunks w and w+4 (16 rows x 32 cols);
  // lane l -> row chunk*16 + l/4, colseg SWIZZLED: ((l&3)^((l>>3)&3))*8.
  int srow = lane >> 2, scol = ((lane & 3) ^ ((lane >> 3) & 3)) * 8;
  const u16* Bg0 = &Bt[(size_t)(n0 + w * 16 + srow) * Dn + scol];
  const u16* Bg1 = &Bt[(size_t)(n0 + (w + 4) * 16 + srow) * Dn + scol];
  int bread = (g ^ ((lr >> 1) & 3)) * 8;   // swizzled read colseg

  float4 a0a = *(const float4*)Ap0, a0b = *(const float4*)(Ap0 + 4);
  float4 a1a = *(const float4*)Ap1, a1b = *(const float4*)(Ap1 + 4);
  // prologue: stage tile 0 (A write + B gload), issue A-regs for tile 1
  gload16(Bg0, &BlL[0][(size_t)w * 512]);
  gload16(Bg1, &BlL[0][(size_t)(w + 4) * 512]);
  {
    union { u16 s[8]; int4 v; } c0, c1;
    c0.s[0]=f2bf(a0a.x); c0.s[1]=f2bf(a0a.y); c0.s[2]=f2bf(a0a.z); c0.s[3]=f2bf(a0a.w);
    c0.s[4]=f2bf(a0b.x); c0.s[5]=f2bf(a0b.y); c0.s[6]=f2bf(a0b.z); c0.s[7]=f2bf(a0b.w);
    c1.s[0]=f2bf(a1a.x); c1.s[1]=f2bf(a1a.y); c1.s[2]=f2bf(a1a.z); c1.s[3]=f2bf(a1a.w);
    c1.s[4]=f2bf(a1b.x); c1.s[5]=f2bf(a1b.y); c1.s[6]=f2bf(a1b.z); c1.s[7]=f2bf(a1b.w);
    *(int4*)&AlP[0][sr][sc*8]      = c0.v;
    *(int4*)&AlP[0][sr + 64][sc*8] = c1.v;
  }
  a0a = *(const float4*)(Ap0 + 32); a0b = *(const float4*)(Ap0 + 36);
  a1a = *(const float4*)(Ap1 + 32); a1b = *(const float4*)(Ap1 + 36);
  __syncthreads();

  for (int t = 0; t < 32; t++) {
    int cur = t & 1;
    if (t + 1 < 32) {
      int kn = (t + 1) * 32;
      gload16(Bg0 + kn, &BlL[cur ^ 1][(size_t)w * 512]);
      gload16(Bg1 + kn, &BlL[cur ^ 1][(size_t)(w + 4) * 512]);
      union { u16 s[8]; int4 v; } c0, c1;
      c0.s[0]=f2bf(a0a.x); c0.s[1]=f2bf(a0a.y); c0.s[2]=f2bf(a0a.z); c0.s[3]=f2bf(a0a.w);
      c0.s[4]=f2bf(a0b.x); c0.s[5]=f2bf(a0b.y); c0.s[6]=f2bf(a0b.z); c0.s[7]=f2bf(a0b.w);
      c1.s[0]=f2bf(a1a.x); c1.s[1]=f2bf(a1a.y); c1.s[2]=f2bf(a1a.z); c1.s[3]=f2bf(a1a.w);
      c1.s[4]=f2bf(a1b.x); c1.s[5]=f2bf(a1b.y); c1.s[6]=f2bf(a1b.z); c1.s[7]=f2bf(a1b.w);
      *(int4*)&AlP[cur ^ 1][sr][sc*8]      = c0.v;
      *(int4*)&AlP[cur ^ 1][sr + 64][sc*8] = c1.v;
      if (t + 2 < 32) {
        int kf = (t + 2) * 32;
        a0a = *(const float4*)(Ap0 + kf); a0b = *(const float4*)(Ap0 + kf + 4);
        a1a = *(const float4*)(Ap1 + kf); a1b = *(const float4*)(Ap1 + kf + 4);
      }
    }
    bf16x8 a[4], b[4];
    #pragma unroll
    for (int mi = 0; mi < 4; mi++) a[mi] = *(const bf16x8*)&AlP[cur][wr*64 + mi*16 + lr][g*8];
    #pragma unroll
    for (int ni = 0; ni < 4; ni++) b[ni] = *(const bf16x8*)&BlL[cur][(size_t)(wc*64 + ni*16 + lr) * 32 + bread];
    #pragma unroll
    for (int mi = 0; mi < 4; mi++)
      #pragma unroll
      for (int ni = 0; ni < 4; ni++)
        acc[mi][ni] = mfma16(a[mi], b[ni], acc[mi][ni]);
    __syncthreads();
  }
  #pragma unroll
  for (int mi = 0; mi < 4; mi++)
    #pragma unroll
    for (int ni = 0; ni < 4; ni++) {
      int row0 = m0 + wr*64 + mi*16 + g*4;
      int col = n0 + wc*64 + ni*16 + lr;
      int bb = row0 >> 10, tt0 = row0 & 1023;
      int hh = col >> 6, dd = col & 63;
      if (hh < 16) {
        u16* p = dst0 + (((size_t)(bb*16 + hh) << 10) + (size_t)tt0) * 64 + dd;
        #pragma unroll
        for (int r = 0; r < 4; r++) p[(size_t)r * 64] = f2bf(acc[mi][ni][r] * scale);
      } else {
        union { u16 s[4]; uint2 u; } o;
        #pragma unroll
        for (int r = 0; r < 4; r++) o.s[r] = f2bf(acc[mi][ni][r]);
        *(uint2*)(Vb + (((size_t)((bb*16 + (hh - 16)) * 64 + dd)) << 10) + tt0) = o.u;
      }
    }
}

// ---------------- O-projection GEMM: dbuf global_load_lds, swizzled source ----------------
__global__ __launch_bounds__(256) void k_gemm_bt(const u16* __restrict__ A, const u16* __restrict__ Bt,
                                                 u16* __restrict__ dst0, const float* __restrict__ bias) {
  __shared__ __align__(16) u16 AlL[2][128 * 32];
  __shared__ __align__(16) u16 BlL[2][128 * 32];
  int m0 = blockIdx.y * 128, n0 = blockIdx.x * 128;
  int tid = threadIdx.x;
  int w = tid >> 6, lane = tid & 63, g = lane >> 4, lr = lane & 15;
  int wr = w >> 1, wc = w & 1;
  f32x4 acc[4][4] = {};
  int srow = lane >> 2, scol = ((lane & 3) ^ ((lane >> 3) & 3)) * 8;  // pre-swizzled source
  const u16* Ag0 = &A[(size_t)(m0 + w * 16 + srow) * Dn + scol];
  const u16* Ag1 = &A[(size_t)(m0 + (w + 4) * 16 + srow) * Dn + scol];
  const u16* Bg0 = &Bt[(size_t)(n0 + w * 16 + srow) * Dn + scol];
  const u16* Bg1 = &Bt[(size_t)(n0 + (w + 4) * 16 + srow) * Dn + scol];
  int bread = (g ^ ((lr >> 1) & 3)) * 8;   // swizzled read colseg

  // prologue: stage tile 0
  gload16(Ag0, &AlL[0][(size_t)w * 512]);
  gload16(Ag1, &AlL[0][(size_t)(w + 4) * 512]);
  gload16(Bg0, &BlL[0][(size_t)w * 512]);
  gload16(Bg1, &BlL[0][(size_t)(w + 4) * 512]);
  __syncthreads();

  for (int t = 0; t < 32; t++) {
    int cur = t & 1;
    if (t + 1 < 32) {
      int kn = (t + 1) * 32;
      gload16(Ag0 + kn, &AlL[cur ^ 1][(size_t)w * 512]);
      gload16(Ag1 + kn, &AlL[cur ^ 1][(size_t)(w + 4) * 512]);
      gload16(Bg0 + kn, &BlL[cur ^ 1][(size_t)w * 512]);
      gload16(Bg1 + kn, &BlL[cur ^ 1][(size_t)(w + 4) * 512]);
    }
    bf16x8 a[4], b[4];
    #pragma unroll
    for (int mi = 0; mi < 4; mi++) a[mi] = *(const bf16x8*)&AlL[cur][(size_t)(wr*64 + mi*16 + lr) * 32 + bread];
    #pragma unroll
    for (int ni = 0; ni < 4; ni++) b[ni] = *(const bf16x8*)&BlL[cur][(size_t)(wc*64 + ni*16 + lr) * 32 + bread];
    #pragma unroll
    for (int mi = 0; mi < 4; mi++)
      #pragma unroll
      for (int ni = 0; ni < 4; ni++)
        acc[mi][ni] = mfma16(a[mi], b[ni], acc[mi][ni]);
    __syncthreads();
  }
  #pragma unroll
  for (int mi = 0; mi < 4; mi++)
    #pragma unroll
    for (int ni = 0; ni < 4; ni++) {
      int row0 = m0 + wr*64 + mi*16 + g*4;
      int col = n0 + wc*64 + ni*16 + lr;
      #pragma unroll
      for (int r = 0; r < 4; r++)
        dst0[(size_t)(row0 + r) * Dn + col] = f2bf(acc[mi][ni][r] + bias[col]);
    }
}

// ---------------- flash attention with Music-Transformer skew ----------------
// grid (B, H, T/128), block 256 = 4 waves; 512 blocks -> up to 3 blocks/CU
// (LDS 42.2 KB) with INDEPENDENT barrier domains: while one block drains its
// staging barrier, the other two compute. NO VGPR cap (r11's failure was the
// __launch_bounds__(256,3) 84-reg cap -> 300 MB spill; live range needs ~140).
// Wave inner loop identical to r12: QBLK=32 (two 16-row halves), shared K/V
// fragments + REL E-loads, fixed-max softmax, ones-MFMA row-sum, XOR-swizzled
// K, r6 load-order discipline (mask+E L2 loads before HBM prefetch).
__global__ __launch_bounds__(256) void k_attn(const u16* __restrict__ Qb, const u16* __restrict__ Kb,
                                              const u16* __restrict__ VT, const u16* __restrict__ Eb,
                                              const unsigned long long* __restrict__ mbits,
                                              u16* __restrict__ ctx) {
  __shared__ __align__(16) u16 KlF[128 * 64];
  __shared__ __align__(16) u16 Vt[64][136];
  __shared__ __align__(16) u16 RP[4][16][72];
  int h = blockIdx.y;
  int b = blockIdx.x;
  int q0 = blockIdx.z * 128;
  int tid = threadIdx.x;
  int w = tid >> 6, lane = tid & 63, g = lane >> 4, lr = lane & 15;
  int qw0 = q0 + w * 32;
  size_t headoff = (size_t)(b * Hn + h) * Tn * DHn;
  bf16x8 qf0 = *(const bf16x8*)&Qb[headoff + (size_t)(qw0 + lr)*64 + g*8];
  bf16x8 qf1 = *(const bf16x8*)&Qb[headoff + (size_t)(qw0 + lr)*64 + 32 + g*8];
  bf16x8 qf2 = *(const bf16x8*)&Qb[headoff + (size_t)(qw0 + 16 + lr)*64 + g*8];
  bf16x8 qf3 = *(const bf16x8*)&Qb[headoff + (size_t)(qw0 + 16 + lr)*64 + 32 + g*8];
  f32x4 O[8] = {};
  f32x4 Os0 = {0.f, 0.f, 0.f, 0.f}, Os1 = {0.f, 0.f, 0.f, 0.f};
  union { u16 s[8]; bf16x8 v; } one8;
  #pragma unroll
  for (int j = 0; j < 8; j++) one8.s[j] = 0x3F80u;

  int srcl[4]; bool psel[4];
  #pragma unroll
  for (int r = 0; r < 4; r++) {
    int rowq = g*4 + r;
    srcl[r] = (lane & 48) + ((lr - rowq + 15) & 15);
    psel[r] = (lr <= rowq);
  }
  const unsigned long long* mrow = mbits + ((size_t)(b * Tn + qw0 + g*4) << 4);

  f32x4 carry0 = {0.f, 0.f, 0.f, 0.f}, carry1 = {0.f, 0.f, 0.f, 0.f};
  {
    int rm = 1008 - qw0;
    const u16* ep = &Eb[(size_t)(rm + lr) * 64 + g*8];
    carry0 = mfma16(qf0, *(const bf16x8*)ep, carry0);
    carry0 = mfma16(qf1, *(const bf16x8*)(ep + 32), carry0);
    const u16* ep1 = &Eb[(size_t)(rm - 16 + lr) * 64 + g*8];
    carry1 = mfma16(qf2, *(const bf16x8*)ep1, carry1);
    carry1 = mfma16(qf3, *(const bf16x8*)(ep1 + 32), carry1);
  }

  // staging (256 threads, 128-kv iter):
  //   K: rows sKr+{0,32,64,96}, colseg (tid&7)*8; XOR swizzle preserved
  //     ((sKr+32k)&7 == sKr&7). V^T: rows sVr+{0,16,32,48}, colseg (tid&15)*8.
  int sKr = tid >> 3, sKc = (tid & 7) * 8;
  int kswz = sKc ^ ((sKr & 7) << 3);
  int sVr = tid >> 4, sVc = (tid & 15) * 8;
  const u16* Kgs = Kb + headoff + (size_t)sKr * 64 + sKc;
  const u16* Vgs = VT + headoff + (size_t)sVr * 1024 + sVc;
  int4 kA = *(const int4*)Kgs;
  int4 kB = *(const int4*)(Kgs + (size_t)32 * 64);
  int4 kC = *(const int4*)(Kgs + (size_t)64 * 64);
  int4 kD = *(const int4*)(Kgs + (size_t)96 * 64);
  int4 vA = *(const int4*)Vgs;
  int4 vB = *(const int4*)(Vgs + 16 * 1024);
  int4 vC = *(const int4*)(Vgs + 32 * 1024);
  int4 vD = *(const int4*)(Vgs + 48 * 1024);

  int kread = (g * 8) ^ ((lr & 7) << 3);
  int kread2 = (32 + g * 8) ^ ((lr & 7) << 3);

  for (int k0 = 0; k0 < Tn; k0 += 128) {
    __syncthreads();
    *(int4*)&KlF[sKr * 64 + kswz]        = kA;
    *(int4*)&KlF[(sKr + 32) * 64 + kswz] = kB;
    *(int4*)&KlF[(sKr + 64) * 64 + kswz] = kC;
    *(int4*)&KlF[(sKr + 96) * 64 + kswz] = kD;
    *(int4*)&Vt[sVr][sVc]                = vA;
    *(int4*)&Vt[sVr + 16][sVc]           = vB;
    *(int4*)&Vt[sVr + 32][sVc]           = vC;
    *(int4*)&Vt[sVr + 48][sVc]           = vD;
    __syncthreads();

    uint2 mw0[2][4], mw1[2][4];
    #pragma unroll
    for (int t = 0; t < 2; t++)
      #pragma unroll
      for (int r = 0; r < 4; r++) {
        mw0[t][r] = *(const uint2*)(mrow + (size_t)r * 16 + (k0 >> 6) + t);
        mw1[t][r] = *(const uint2*)(mrow + 256 + (size_t)r * 16 + (k0 >> 6) + t);
      }

    int rmin0 = k0 - qw0 + 1008;
    bf16x8 pa000, pa001, pa010, pa011;
    bf16x8 pa100, pa101, pa110, pa111;

    bf16x8 e0[5][2];
    #pragma unroll
    for (int j = 0; j < 5; j++) {
      const u16* ep = &Eb[(size_t)(rmin0 + j*16 + lr) * 64 + g*8];
      e0[j][0] = *(const bf16x8*)ep;
      e0[j][1] = *(const bf16x8*)(ep + 32);
    }
    f32x4 Rm0[5], Rn0[5];
    Rm0[0] = carry0;
    Rn0[0] = carry1;
    __builtin_amdgcn_s_setprio(1);
    #pragma unroll
    for (int j = 1; j < 5; j++) {
      f32x4 R = {0.f, 0.f, 0.f, 0.f};
      R = mfma16(qf0, e0[j][0], R);
      R = mfma16(qf1, e0[j][1], R);
      Rm0[j] = R;
      f32x4 R2 = {0.f, 0.f, 0.f, 0.f};
      R2 = mfma16(qf2, e0[j-1][0], R2);
      R2 = mfma16(qf3, e0[j-1][1], R2);
      Rn0[j] = R2;
    }
    f32x4 S0[4], T0[4];
    #pragma unroll
    for (int c = 0; c < 4; c++) {
      int krow = c*16 + lr;
      bf16x8 kf0 = *(const bf16x8*)&KlF[krow*64 + kread];
      bf16x8 kf1 = *(const bf16x8*)&KlF[krow*64 + kread2];
      f32x4 z = {0.f, 0.f, 0.f, 0.f};
      z = mfma16(qf0, kf0, z); z = mfma16(qf1, kf1, z);
      S0[c] = z;
      f32x4 z2 = {0.f, 0.f, 0.f, 0.f};
      z2 = mfma16(qf2, kf0, z2); z2 = mfma16(qf3, kf1, z2);
      T0[c] = z2;
    }
    __builtin_amdgcn_s_setprio(0);
    {
      float sh[5][4], si[5][4];
      #pragma unroll
      for (int s5 = 0; s5 < 5; s5++)
        #pragma unroll
        for (int r = 0; r < 4; r++) {
          sh[s5][r] = __shfl(Rm0[s5][r], srcl[r], 64);
          si[s5][r] = __shfl(Rn0[s5][r], srcl[r], 64);
        }
      #pragma unroll
      for (int c = 0; c < 4; c++)
        #pragma unroll
        for (int r = 0; r < 4; r++) {
          float s = S0[c][r] + (psel[r] ? sh[c][r] : sh[c+1][r]);
          unsigned bit;
          if (c == 0)      bit = (mw0[0][r].x >> lr) & 1u;
          else if (c == 1) bit = (mw0[0][r].x >> (16 + lr)) & 1u;
          else if (c == 2) bit = (mw0[0][r].y >> lr) & 1u;
          else             bit = (mw0[0][r].y >> (16 + lr)) & 1u;
          s = bit ? -1e9f : s;
          RP[w][g*4 + r][c*16 + lr] = f2bf(__builtin_amdgcn_exp2f(s));
        }
      pa000 = *(const bf16x8*)&RP[w][lr][g*8];
      pa001 = *(const bf16x8*)&RP[w][lr][32 + g*8];
      #pragma unroll
      for (int c = 0; c < 4; c++)
        #pragma unroll
        for (int r = 0; r < 4; r++) {
          float s = T0[c][r] + (psel[r] ? si[c][r] : si[c+1][r]);
          unsigned bit;
          if (c == 0)      bit = (mw1[0][r].x >> lr) & 1u;
          else if (c == 1) bit = (mw1[0][r].x >> (16 + lr)) & 1u;
          else if (c == 2) bit = (mw1[0][r].y >> lr) & 1u;
          else             bit = (mw1[0][r].y >> (16 + lr)) & 1u;
          s = bit ? -1e9f : s;
          RP[w][g*4 + r][c*16 + lr] = f2bf(__builtin_amdgcn_exp2f(s));
        }
      pa010 = *(const bf16x8*)&RP[w][lr][g*8];
      pa011 = *(const bf16x8*)&RP[w][lr][32 + g*8];
    }

    bf16x8 e1[5][2];
    #pragma unroll
    for (int j = 0; j < 5; j++) {
      const u16* ep = &Eb[(size_t)(rmin0 + 64 + j*16 + lr) * 64 + g*8];
      e1[j][0] = *(const bf16x8*)ep;
      e1[j][1] = *(const bf16x8*)(ep + 32);
    }
    f32x4 Rm1[5], Rn1[5];
    Rm1[0] = Rm0[4];
    Rn1[0] = Rn0[4];
    __builtin_amdgcn_s_setprio(1);
    #pragma unroll
    for (int j = 1; j < 5; j++) {
      f32x4 R = {0.f, 0.f, 0.f, 0.f};
      R = mfma16(qf0, e1[j][0], R);
      R = mfma16(qf1, e1[j][1], R);
      Rm1[j] = R;
      f32x4 R2 = {0.f, 0.f, 0.f, 0.f};
      R2 = mfma16(qf2, e1[j-1][0], R2);
      R2 = mfma16(qf3, e1[j-1][1], R2);
      Rn1[j] = R2;
    }
    __builtin_amdgcn_s_setprio(0);
    carry0 = Rm1[4];
    carry1 = Rn1[4];

    __builtin_amdgcn_sched_barrier(0);
    if (k0 + 128 < Tn) {
      kA = *(const int4*)(Kgs + (size_t)(k0 + 128) * 64);
      kB = *(const int4*)(Kgs + (size_t)(k0 + 160) * 64);
      kC = *(const int4*)(Kgs + (size_t)(k0 + 192) * 64);
      kD = *(const int4*)(Kgs + (size_t)(k0 + 224) * 64);
      vA = *(const int4*)(Vgs + k0 + 128);
      vB = *(const int4*)(Vgs + 16 * 1024 + k0 + 128);
      vC = *(const int4*)(Vgs + 32 * 1024 + k0 + 128);
      vD = *(const int4*)(Vgs + 48 * 1024 + k0 + 128);
    }
    __builtin_amdgcn_sched_barrier(0);

    f32x4 S1[4], T1[4];
    __builtin_amdgcn_s_setprio(1);
    #pragma unroll
    for (int c = 0; c < 4; c++) {
      int krow = 64 + c*16 + lr;
      bf16x8 kf0 = *(const bf16x8*)&KlF[krow*64 + kread];
      bf16x8 kf1 = *(const bf16x8*)&KlF[krow*64 + kread2];
      f32x4 z = {0.f, 0.f, 0.f, 0.f};
      z = mfma16(qf0, kf0, z); z = mfma16(qf1, kf1, z);
      S1[c] = z;
      f32x4 z2 = {0.f, 0.f, 0.f, 0.f};
      z2 = mfma16(qf2, kf0, z2); z2 = mfma16(qf3, kf1, z2);
      T1[c] = z2;
    }
    __builtin_amdgcn_s_setprio(0);
    {
      float sh[5][4], si[5][4];
      #pragma unroll
      for (int s5 = 0; s5 < 5; s5++)
        #pragma unroll
        for (int r = 0; r < 4; r++) {
          sh[s5][r] = __shfl(Rm1[s5][r], srcl[r], 64);
          si[s5][r] = __shfl(Rn1[s5][r], srcl[r], 64);
        }
      #pragma unroll
      for (int c = 0; c < 4; c++)
        #pragma unroll
        for (int r = 0; r < 4; r++) {
          float s = S1[c][r] + (psel[r] ? sh[c][r] : sh[c+1][r]);
          unsigned bit;
          if (c == 0)      bit = (mw0[1][r].x >> lr) & 1u;
          else if (c == 1) bit = (mw0[1][r].x >> (16 + lr)) & 1u;
          else if (c == 2) bit = (mw0[1][r].y >> lr) & 1u;
          else             bit = (mw0[1][r].y >> (16 + lr)) & 1u;
          s = bit ? -1e9f : s;
          RP[w][g*4 + r][c*16 + lr] = f2bf(__builtin_amdgcn_exp2f(s));
        }
      pa100 = *(const bf16x8*)&RP[w][lr][g*8];
      pa101 = *(const bf16x8*)&RP[w][lr][32 + g*8];
      #pragma unroll
      for (int c = 0; c < 4; c++)
        #pragma unroll
        for (int r = 0; r < 4; r++) {
          float s = T1[c][r] + (psel[r] ? si[c][r] : si[c+1][r]);
          unsigned bit;
          if (c == 0)      bit = (mw1[1][r].x >> lr) & 1u;
          else if (c == 1) bit = (mw1[1][r].x >> (16 + lr)) & 1u;
          else if (c == 2) bit = (mw1[1][r].y >> lr) & 1u;
          else             bit = (mw1[1][r].y >> (16 + lr)) & 1u;
          s = bit ? -1e9f : s;
          RP[w][g*4 + r][c*16 + lr] = f2bf(__builtin_amdgcn_exp2f(s));
        }
      pa110 = *(const bf16x8*)&RP[w][lr][g*8];
      pa111 = *(const bf16x8*)&RP[w][lr][32 + g*8];
    }

    __builtin_amdgcn_s_setprio(1);
    #pragma unroll
    for (int ct = 0; ct < 4; ct++) {
      bf16x8 vf0 = *(const bf16x8*)&Vt[ct*16 + lr][g*8];
      bf16x8 vf1 = *(const bf16x8*)&Vt[ct*16 + lr][32 + g*8];
      bf16x8 vf2 = *(const bf16x8*)&Vt[ct*16 + lr][64 + g*8];
      bf16x8 vf3 = *(const bf16x8*)&Vt[ct*16 + lr][96 + g*8];
      O[ct] = mfma16(pa000, vf0, O[ct]);
      O[ct] = mfma16(pa001, vf1, O[ct]);
      O[ct] = mfma16(pa100, vf2, O[ct]);
      O[ct] = mfma16(pa101, vf3, O[ct]);
      O[4+ct] = mfma16(pa010, vf0, O[4+ct]);
      O[4+ct] = mfma16(pa011, vf1, O[4+ct]);
      O[4+ct] = mfma16(pa110, vf2, O[4+ct]);
      O[4+ct] = mfma16(pa111, vf3, O[4+ct]);
    }
    Os0 = mfma16(pa000, one8.v, Os0);
    Os0 = mfma16(pa001, one8.v, Os0);
    Os0 = mfma16(pa100, one8.v, Os0);
    Os0 = mfma16(pa101, one8.v, Os0);
    Os1 = mfma16(pa010, one8.v, Os1);
    Os1 = mfma16(pa011, one8.v, Os1);
    Os1 = mfma16(pa110, one8.v, Os1);
    Os1 = mfma16(pa111, one8.v, Os1);
    __builtin_amdgcn_s_setprio(0);
  }
  float inv0[4], inv1[4];
  #pragma unroll
  for (int r = 0; r < 4; r++) { inv0[r] = 1.f / Os0[r]; inv1[r] = 1.f / Os1[r]; }
  #pragma unroll
  for (int ct = 0; ct < 4; ct++)
    #pragma unroll
    for (int r = 0; r < 4; r++) {
      int rowq = g*4 + r, col = ct*16 + lr;
      ctx[(size_t)(b*Tn + qw0 + rowq) * 1024 + h*64 + col] = f2bf(O[ct][r] * inv0[r]);
      ctx[(size_t)(b*Tn + qw0 + 16 + rowq) * 1024 + h*64 + col] = f2bf(O[4+ct][r] * inv1[r]);
    }
}

// ---------------- residual + LayerNorm ----------------
__global__ __launch_bounds__(256) void k_ln(const float* __restrict__ x, const u16* __restrict__ o,
                                            const float* __restrict__ gamma, const float* __restrict__ beta,
                                            float* __restrict__ out) {
  int m = blockIdx.x, tid = threadIdx.x;
  int w = tid >> 6, lane = tid & 63;
  const float* xr = x + (size_t)m * Dn;
  const u16* orow = o + (size_t)m * Dn;
  float4 xv = *(const float4*)&xr[tid*4];
  union { uint2 u; u16 s[4]; } ou;
  ou.u = *(const uint2*)&orow[tid*4];
  float y[4];
  y[0] = xv.x + bf2f(ou.s[0]);
  y[1] = xv.y + bf2f(ou.s[1]);
  y[2] = xv.z + bf2f(ou.s[2]);
  y[3] = xv.w + bf2f(ou.s[3]);
  float s = y[0]+y[1]+y[2]+y[3];
  float s2 = y[0]*y[0]+y[1]*y[1]+y[2]*y[2]+y[3]*y[3];
  #pragma unroll
  for (int off = 1; off < 64; off <<= 1) { s += __shfl_xor(s, off); s2 += __shfl_xor(s2, off); }
  __shared__ float red[8];
  if (lane == 0) { red[w] = s; red[4 + w] = s2; }
  __syncthreads();
  float Sa = red[0]+red[1]+red[2]+red[3];
  float Sb = red[4]+red[5]+red[6]+red[7];
  float mu = Sa * (1.f/1024.f);
  float var = Sb * (1.f/1024.f) - mu*mu;
  float rstd = rsqrtf(var + 1e-5f);
  #pragma unroll
  for (int i = 0; i < 4; i++) {
    int j = tid*4 + i;
    out[(size_t)m*Dn + j] = (y[i] - mu) * rstd * gamma[j] + beta[j];
  }
}

extern "C" void kernel_launch(void* const* d_in, const int* in_sizes, int n_in,
                              void* d_out, int out_size, void* d_ws, size_t ws_size,
                              hipStream_t stream) {
  const float* x    = (const float*)d_in[0];
  const float* ctxI = (const float*)d_in[1];
  const unsigned char* mask = (const unsigned char*)d_in[2];
  const float* lut  = (const float*)d_in[3];
  const float* Wq   = (const float*)d_in[4];
  const float* Wk   = (const float*)d_in[5];
  const float* Wv   = (const float*)d_in[6];
  const float* Wo   = (const float*)d_in[7];
  const float* bo   = (const float*)d_in[8];
  const float* gamma= (const float*)d_in[9];
  const float* beta = (const float*)d_in[10];
  float* out = (float*)d_out;

  u16* WqT  = (u16*)d_ws;
  u16* WkT  = WqT + 1048576;
  u16* WvT  = WkT + 1048576;   // contiguous with WkT -> fused KV GEMM reads [2048][1024]
  u16* WoT  = WvT + 1048576;
  u16* Ebf  = WoT + 1048576;
  u16* Qbf  = Ebf + 131072;
  u16* Kbf  = Qbf + 4194304;
  u16* Vbf  = Kbf + 4194304;   // holds V^T [B,H,DH,T]
  u16* ctxb = Vbf + 4194304;
  u16* obf  = ctxb + 4194304;
  unsigned long long* mbits = (unsigned long long*)(obf + 4194304); // 65536 words = 512 KB

  k_maskpack<<<16384, 256, 0, stream>>>(mask, mbits);
  k_convert<<<128, 256, 0, stream>>>(lut, Ebf, 131008);
  dim3 tb(32, 8), tg4(32, 32, 4);
  k_transpose_convert4<<<tg4, tb, 0, stream>>>(Wq, Wk, Wv, Wo, WqT, WkT, WvT, WoT);
  k_proj<<<768, 256, 0, stream>>>(x, ctxI, WqT, WkT, Qbf, Kbf, Vbf);
  k_attn<<<dim3(4, 16, 8), 256, 0, stream>>>(Qbf, Kbf, Vbf, Ebf, mbits, ctxb);
  k_gemm_bt<<<dim3(8, 32), 256, 0, stream>>>(ctxb, WoT, obf, bo);
  k_ln<<<4096, 256, 0, stream>>>(x, obf, gamma, beta, out);
}

// Round 14
// 156.218 us; speedup vs baseline: 1.1774x; 1.1774x over previous
//
#include <hip/hip_runtime.h>

#define Tn 1024
#define Hn 16
#define Dn 1024
#define DHn 64
// SCALE * log2(e): Q is pre-scaled by this, softmax then uses exp2 directly.
#define QSCALE 0.18033688011112042f

typedef unsigned short u16;
typedef unsigned long long ull;
typedef __bf16 bf16x8 __attribute__((ext_vector_type(8)));
typedef float f32x4 __attribute__((ext_vector_type(4)));

__device__ __forceinline__ u16 f2bf(float f) {
  union { float f; unsigned u; } v; v.f = f;
  return (u16)((v.u + 0x7FFFu + ((v.u >> 16) & 1u)) >> 16);
}
__device__ __forceinline__ float bf2f(u16 s) {
  union { unsigned u; float f; } v; v.u = ((unsigned)s) << 16;
  return v.f;
}
__device__ __forceinline__ f32x4 mfma16(bf16x8 a, bf16x8 b, f32x4 c) {
  return __builtin_amdgcn_mfma_f32_16x16x32_bf16(a, b, c, 0, 0, 0);
}
// async global->LDS, 16B per lane; LDS dst must be wave-uniform (chunk base).
__device__ __forceinline__ void gload16(const u16* g, u16* l) {
  __builtin_amdgcn_global_load_lds(
      (const __attribute__((address_space(1))) void*)g,
      (__attribute__((address_space(3))) void*)l, 16, 0, 0);
}

// ---------------- convert fp32 -> bf16 (linear) ----------------
__global__ void k_convert(const float* __restrict__ src, u16* __restrict__ dst, int n) {
  int i = (blockIdx.x * blockDim.x + threadIdx.x) * 4;
  if (i >= n) return;
  float4 v = *(const float4*)(src + i);
  union { u16 s[4]; uint2 u; } o;
  o.s[0] = f2bf(v.x); o.s[1] = f2bf(v.y); o.s[2] = f2bf(v.z); o.s[3] = f2bf(v.w);
  *(uint2*)(dst + i) = o.u;
}

// ---------------- pack bool mask bytes -> 64-bit words (bit k = mask[base+k]) ----------------
// Vectorized: 8 bytes/lane (uint2), 8-bit pattern in-register, OR-combined
// across each 8-lane group via 3 shfl_xor steps; one u64 store per group.
__global__ __launch_bounds__(256) void k_maskpack(const unsigned char* __restrict__ m,
                                                  unsigned long long* __restrict__ mb) {
  int t = blockIdx.x * 256 + threadIdx.x;           // handles bytes [8t, 8t+8)
  uint2 v = *(const uint2*)(m + ((size_t)t << 3));
  unsigned long long m8 = 0;
  #pragma unroll
  for (int j = 0; j < 4; j++) {
    if ((v.x >> (8*j)) & 0xFFu) m8 |= 1ull << j;
    if ((v.y >> (8*j)) & 0xFFu) m8 |= 1ull << (4 + j);
  }
  unsigned long long wv = m8 << ((t & 7) * 8);
  wv |= __shfl_xor(wv, 1);
  wv |= __shfl_xor(wv, 2);
  wv |= __shfl_xor(wv, 4);
  if ((t & 7) == 0) mb[t >> 3] = wv;
}

// ---------------- transpose + convert x4: W[K][N] fp32 -> Wt[N][K] bf16 ----------------
__global__ void k_transpose_convert4(const float* __restrict__ W0, const float* __restrict__ W1,
                                     const float* __restrict__ W2, const float* __restrict__ W3,
                                     u16* __restrict__ T0, u16* __restrict__ T1,
                                     u16* __restrict__ T2, u16* __restrict__ T3) {
  __shared__ float tile[32][33];
  int z = blockIdx.z;
  const float* W = (z == 0) ? W0 : (z == 1) ? W1 : (z == 2) ? W2 : W3;
  u16* Wt = (z == 0) ? T0 : (z == 1) ? T1 : (z == 2) ? T2 : T3;
  int n0 = blockIdx.x * 32, k0 = blockIdx.y * 32;
  int tx = threadIdx.x, ty = threadIdx.y; // (32,8)
  #pragma unroll
  for (int i = 0; i < 4; i++)
    tile[ty + 8*i][tx] = W[(size_t)(k0 + ty + 8*i) * Dn + n0 + tx];
  __syncthreads();
  #pragma unroll
  for (int i = 0; i < 4; i++)
    Wt[(size_t)(n0 + ty + 8*i) * Dn + k0 + tx] = f2bf(tile[tx][ty + 8*i]);
}

// ---------------- merged Q/KV projection GEMM ----------------
// A fp32 reg-staged+converted (padded LDS, 2-way ok); B bf16 via double-buffered
// global_load_lds, LINEAR LDS with PRE-SWIZZLED GLOBAL SOURCE (rule #21).
__global__ __launch_bounds__(256) void k_proj(const float* __restrict__ x, const float* __restrict__ ctxI,
                                              const u16* __restrict__ WqT, const u16* __restrict__ WkvT,
                                              u16* __restrict__ Qb, u16* __restrict__ Kb, u16* __restrict__ Vb) {
  __shared__ __align__(16) u16 AlP[2][128][40];
  __shared__ __align__(16) u16 BlL[2][128 * 32];
  int bx = blockIdx.x;
  bool isQ = bx < 256;
  int idx = isQ ? bx : bx - 256;
  int m0 = (idx & 31) * 128;
  int n0 = (idx >> 5) * 128;
  const float* A = isQ ? x : ctxI;
  const u16* Bt = isQ ? WqT : WkvT;
  u16* dst0 = isQ ? Qb : Kb;
  float scale = isQ ? QSCALE : 1.0f;
  int tid = threadIdx.x;
  int w = tid >> 6, lane = tid & 63, g = lane >> 4, lr = lane & 15;
  int wr = w >> 1, wc = w & 1;
  f32x4 acc[4][4] = {};
  int sr = tid >> 2, sc = tid & 3;
  const float* Ap0 = &A[(size_t)(m0 + sr) * Dn + sc * 8];
  const float* Ap1 = Ap0 + (size_t)64 * Dn;
  int srow = lane >> 2, scol = ((lane & 3) ^ ((lane >> 3) & 3)) * 8;
  const u16* Bg0 = &Bt[(size_t)(n0 + w * 16 + srow) * Dn + scol];
  const u16* Bg1 = &Bt[(size_t)(n0 + (w + 4) * 16 + srow) * Dn + scol];
  int bread = (g ^ ((lr >> 1) & 3)) * 8;   // swizzled read colseg

  float4 a0a = *(const float4*)Ap0, a0b = *(const float4*)(Ap0 + 4);
  float4 a1a = *(const float4*)Ap1, a1b = *(const float4*)(Ap1 + 4);
  gload16(Bg0, &BlL[0][(size_t)w * 512]);
  gload16(Bg1, &BlL[0][(size_t)(w + 4) * 512]);
  {
    union { u16 s[8]; int4 v; } c0, c1;
    c0.s[0]=f2bf(a0a.x); c0.s[1]=f2bf(a0a.y); c0.s[2]=f2bf(a0a.z); c0.s[3]=f2bf(a0a.w);
    c0.s[4]=f2bf(a0b.x); c0.s[5]=f2bf(a0b.y); c0.s[6]=f2bf(a0b.z); c0.s[7]=f2bf(a0b.w);
    c1.s[0]=f2bf(a1a.x); c1.s[1]=f2bf(a1a.y); c1.s[2]=f2bf(a1a.z); c1.s[3]=f2bf(a1a.w);
    c1.s[4]=f2bf(a1b.x); c1.s[5]=f2bf(a1b.y); c1.s[6]=f2bf(a1b.z); c1.s[7]=f2bf(a1b.w);
    *(int4*)&AlP[0][sr][sc*8]      = c0.v;
    *(int4*)&AlP[0][sr + 64][sc*8] = c1.v;
  }
  a0a = *(const float4*)(Ap0 + 32); a0b = *(const float4*)(Ap0 + 36);
  a1a = *(const float4*)(Ap1 + 32); a1b = *(const float4*)(Ap1 + 36);
  __syncthreads();

  for (int t = 0; t < 32; t++) {
    int cur = t & 1;
    if (t + 1 < 32) {
      int kn = (t + 1) * 32;
      gload16(Bg0 + kn, &BlL[cur ^ 1][(size_t)w * 512]);
      gload16(Bg1 + kn, &BlL[cur ^ 1][(size_t)(w + 4) * 512]);
      union { u16 s[8]; int4 v; } c0, c1;
      c0.s[0]=f2bf(a0a.x); c0.s[1]=f2bf(a0a.y); c0.s[2]=f2bf(a0a.z); c0.s[3]=f2bf(a0a.w);
      c0.s[4]=f2bf(a0b.x); c0.s[5]=f2bf(a0b.y); c0.s[6]=f2bf(a0b.z); c0.s[7]=f2bf(a0b.w);
      c1.s[0]=f2bf(a1a.x); c1.s[1]=f2bf(a1a.y); c1.s[2]=f2bf(a1a.z); c1.s[3]=f2bf(a1a.w);
      c1.s[4]=f2bf(a1b.x); c1.s[5]=f2bf(a1b.y); c1.s[6]=f2bf(a1b.z); c1.s[7]=f2bf(a1b.w);
      *(int4*)&AlP[cur ^ 1][sr][sc*8]      = c0.v;
      *(int4*)&AlP[cur ^ 1][sr + 64][sc*8] = c1.v;
      if (t + 2 < 32) {
        int kf = (t + 2) * 32;
        a0a = *(const float4*)(Ap0 + kf); a0b = *(const float4*)(Ap0 + kf + 4);
        a1a = *(const float4*)(Ap1 + kf); a1b = *(const float4*)(Ap1 + kf + 4);
      }
    }
    bf16x8 a[4], b[4];
    #pragma unroll
    for (int mi = 0; mi < 4; mi++) a[mi] = *(const bf16x8*)&AlP[cur][wr*64 + mi*16 + lr][g*8];
    #pragma unroll
    for (int ni = 0; ni < 4; ni++) b[ni] = *(const bf16x8*)&BlL[cur][(size_t)(wc*64 + ni*16 + lr) * 32 + bread];
    #pragma unroll
    for (int mi = 0; mi < 4; mi++)
      #pragma unroll
      for (int ni = 0; ni < 4; ni++)
        acc[mi][ni] = mfma16(a[mi], b[ni], acc[mi][ni]);
    __syncthreads();
  }
  #pragma unroll
  for (int mi = 0; mi < 4; mi++)
    #pragma unroll
    for (int ni = 0; ni < 4; ni++) {
      int row0 = m0 + wr*64 + mi*16 + g*4;
      int col = n0 + wc*64 + ni*16 + lr;
      int bb = row0 >> 10, tt0 = row0 & 1023;
      int hh = col >> 6, dd = col & 63;
      if (hh < 16) {
        u16* p = dst0 + (((size_t)(bb*16 + hh) << 10) + (size_t)tt0) * 64 + dd;
        #pragma unroll
        for (int r = 0; r < 4; r++) p[(size_t)r * 64] = f2bf(acc[mi][ni][r] * scale);
      } else {
        union { u16 s[4]; uint2 u; } o;
        #pragma unroll
        for (int r = 0; r < 4; r++) o.s[r] = f2bf(acc[mi][ni][r]);
        *(uint2*)(Vb + (((size_t)((bb*16 + (hh - 16)) * 64 + dd)) << 10) + tt0) = o.u;
      }
    }
}

// ---------------- O-projection GEMM: dbuf global_load_lds, swizzled source ----------------
__global__ __launch_bounds__(256) void k_gemm_bt(const u16* __restrict__ A, const u16* __restrict__ Bt,
                                                 u16* __restrict__ dst0, const float* __restrict__ bias) {
  __shared__ __align__(16) u16 AlL[2][128 * 32];
  __shared__ __align__(16) u16 BlL[2][128 * 32];
  int m0 = blockIdx.y * 128, n0 = blockIdx.x * 128;
  int tid = threadIdx.x;
  int w = tid >> 6, lane = tid & 63, g = lane >> 4, lr = lane & 15;
  int wr = w >> 1, wc = w & 1;
  f32x4 acc[4][4] = {};
  int srow = lane >> 2, scol = ((lane & 3) ^ ((lane >> 3) & 3)) * 8;  // pre-swizzled source
  const u16* Ag0 = &A[(size_t)(m0 + w * 16 + srow) * Dn + scol];
  const u16* Ag1 = &A[(size_t)(m0 + (w + 4) * 16 + srow) * Dn + scol];
  const u16* Bg0 = &Bt[(size_t)(n0 + w * 16 + srow) * Dn + scol];
  const u16* Bg1 = &Bt[(size_t)(n0 + (w + 4) * 16 + srow) * Dn + scol];
  int bread = (g ^ ((lr >> 1) & 3)) * 8;   // swizzled read colseg

  gload16(Ag0, &AlL[0][(size_t)w * 512]);
  gload16(Ag1, &AlL[0][(size_t)(w + 4) * 512]);
  gload16(Bg0, &BlL[0][(size_t)w * 512]);
  gload16(Bg1, &BlL[0][(size_t)(w + 4) * 512]);
  __syncthreads();

  for (int t = 0; t < 32; t++) {
    int cur = t & 1;
    if (t + 1 < 32) {
      int kn = (t + 1) * 32;
      gload16(Ag0 + kn, &AlL[cur ^ 1][(size_t)w * 512]);
      gload16(Ag1 + kn, &AlL[cur ^ 1][(size_t)(w + 4) * 512]);
      gload16(Bg0 + kn, &BlL[cur ^ 1][(size_t)w * 512]);
      gload16(Bg1 + kn, &BlL[cur ^ 1][(size_t)(w + 4) * 512]);
    }
    bf16x8 a[4], b[4];
    #pragma unroll
    for (int mi = 0; mi < 4; mi++) a[mi] = *(const bf16x8*)&AlL[cur][(size_t)(wr*64 + mi*16 + lr) * 32 + bread];
    #pragma unroll
    for (int ni = 0; ni < 4; ni++) b[ni] = *(const bf16x8*)&BlL[cur][(size_t)(wc*64 + ni*16 + lr) * 32 + bread];
    #pragma unroll
    for (int mi = 0; mi < 4; mi++)
      #pragma unroll
      for (int ni = 0; ni < 4; ni++)
        acc[mi][ni] = mfma16(a[mi], b[ni], acc[mi][ni]);
    __syncthreads();
  }
  #pragma unroll
  for (int mi = 0; mi < 4; mi++)
    #pragma unroll
    for (int ni = 0; ni < 4; ni++) {
      int row0 = m0 + wr*64 + mi*16 + g*4;
      int col = n0 + wc*64 + ni*16 + lr;
      #pragma unroll
      for (int r = 0; r < 4; r++)
        dst0[(size_t)(row0 + r) * Dn + col] = f2bf(acc[mi][ni][r] + bias[col]);
    }
}

// ---------------- flash attention with Music-Transformer skew ----------------
// r12 configuration (session best, 69.3 µs): grid (B,H,T/256), block 512 =
// 8 waves; wave owns 32 q-rows (two 16-row halves). Occupancy experiments
// r4/r5/r11/r13 all confirmed the HW pins ~1 block/CU here; 8-wave sharing
// amortizes staging best. 116 VGPR, no spill. Fixed-max softmax, ones-MFMA
// row-sum, XOR-swizzled K, r6 load-order discipline.
__global__ __launch_bounds__(512, 2) void k_attn(const u16* __restrict__ Qb, const u16* __restrict__ Kb,
                                              const u16* __restrict__ VT, const u16* __restrict__ Eb,
                                              const unsigned long long* __restrict__ mbits,
                                              u16* __restrict__ ctx) {
  __shared__ __align__(16) u16 KlF[128 * 64];
  __shared__ __align__(16) u16 Vt[64][136];
  __shared__ __align__(16) u16 RP[8][16][72];
  int h = blockIdx.y;
  int b = blockIdx.x;
  int q0 = blockIdx.z * 256;
  int tid = threadIdx.x;
  int w = tid >> 6, lane = tid & 63, g = lane >> 4, lr = lane & 15;
  int qw0 = q0 + w * 32;
  size_t headoff = (size_t)(b * Hn + h) * Tn * DHn;
  bf16x8 qf0 = *(const bf16x8*)&Qb[headoff + (size_t)(qw0 + lr)*64 + g*8];
  bf16x8 qf1 = *(const bf16x8*)&Qb[headoff + (size_t)(qw0 + lr)*64 + 32 + g*8];
  bf16x8 qf2 = *(const bf16x8*)&Qb[headoff + (size_t)(qw0 + 16 + lr)*64 + g*8];
  bf16x8 qf3 = *(const bf16x8*)&Qb[headoff + (size_t)(qw0 + 16 + lr)*64 + 32 + g*8];
  f32x4 O[8] = {};
  f32x4 Os0 = {0.f, 0.f, 0.f, 0.f}, Os1 = {0.f, 0.f, 0.f, 0.f};
  union { u16 s[8]; bf16x8 v; } one8;
  #pragma unroll
  for (int j = 0; j < 8; j++) one8.s[j] = 0x3F80u;

  int srcl[4]; bool psel[4];
  #pragma unroll
  for (int r = 0; r < 4; r++) {
    int rowq = g*4 + r;
    srcl[r] = (lane & 48) + ((lr - rowq + 15) & 15);
    psel[r] = (lr <= rowq);
  }
  const unsigned long long* mrow = mbits + ((size_t)(b * Tn + qw0 + g*4) << 4);

  f32x4 carry0 = {0.f, 0.f, 0.f, 0.f}, carry1 = {0.f, 0.f, 0.f, 0.f};
  {
    int rm = 1008 - qw0;
    const u16* ep = &Eb[(size_t)(rm + lr) * 64 + g*8];
    carry0 = mfma16(qf0, *(const bf16x8*)ep, carry0);
    carry0 = mfma16(qf1, *(const bf16x8*)(ep + 32), carry0);
    const u16* ep1 = &Eb[(size_t)(rm - 16 + lr) * 64 + g*8];
    carry1 = mfma16(qf2, *(const bf16x8*)ep1, carry1);
    carry1 = mfma16(qf3, *(const bf16x8*)(ep1 + 32), carry1);
  }

  int sKr = tid >> 3, sKc = (tid & 7) * 8;
  int kswz = sKc ^ ((sKr & 7) << 3);
  int sVr = tid >> 4, sVc = (tid & 15) * 8;
  const u16* Kgs = Kb + headoff + (size_t)sKr * 64 + sKc;
  const u16* Vgs = VT + headoff + (size_t)sVr * 1024 + sVc;
  int4 kA = *(const int4*)Kgs;
  int4 kB = *(const int4*)(Kgs + (size_t)64 * 64);
  int4 vA = *(const int4*)Vgs;
  int4 vB = *(const int4*)(Vgs + 32 * 1024);

  int kread = (g * 8) ^ ((lr & 7) << 3);
  int kread2 = (32 + g * 8) ^ ((lr & 7) << 3);

  for (int k0 = 0; k0 < Tn; k0 += 128) {
    __syncthreads();
    *(int4*)&KlF[sKr * 64 + kswz]        = kA;
    *(int4*)&KlF[(sKr + 64) * 64 + kswz] = kB;
    *(int4*)&Vt[sVr][sVc]                = vA;
    *(int4*)&Vt[sVr + 32][sVc]           = vB;
    __syncthreads();

    uint2 mw0[2][4], mw1[2][4];
    #pragma unroll
    for (int t = 0; t < 2; t++)
      #pragma unroll
      for (int r = 0; r < 4; r++) {
        mw0[t][r] = *(const uint2*)(mrow + (size_t)r * 16 + (k0 >> 6) + t);
        mw1[t][r] = *(const uint2*)(mrow + 256 + (size_t)r * 16 + (k0 >> 6) + t);
      }

    int rmin0 = k0 - qw0 + 1008;
    bf16x8 pa000, pa001, pa010, pa011;
    bf16x8 pa100, pa101, pa110, pa111;

    bf16x8 e0[5][2];
    #pragma unroll
    for (int j = 0; j < 5; j++) {
      const u16* ep = &Eb[(size_t)(rmin0 + j*16 + lr) * 64 + g*8];
      e0[j][0] = *(const bf16x8*)ep;
      e0[j][1] = *(const bf16x8*)(ep + 32);
    }
    f32x4 Rm0[5], Rn0[5];
    Rm0[0] = carry0;
    Rn0[0] = carry1;
    __builtin_amdgcn_s_setprio(1);
    #pragma unroll
    for (int j = 1; j < 5; j++) {
      f32x4 R = {0.f, 0.f, 0.f, 0.f};
      R = mfma16(qf0, e0[j][0], R);
      R = mfma16(qf1, e0[j][1], R);
      Rm0[j] = R;
      f32x4 R2 = {0.f, 0.f, 0.f, 0.f};
      R2 = mfma16(qf2, e0[j-1][0], R2);
      R2 = mfma16(qf3, e0[j-1][1], R2);
      Rn0[j] = R2;
    }
    f32x4 S0[4], T0[4];
    #pragma unroll
    for (int c = 0; c < 4; c++) {
      int krow = c*16 + lr;
      bf16x8 kf0 = *(const bf16x8*)&KlF[krow*64 + kread];
      bf16x8 kf1 = *(const bf16x8*)&KlF[krow*64 + kread2];
      f32x4 z = {0.f, 0.f, 0.f, 0.f};
      z = mfma16(qf0, kf0, z); z = mfma16(qf1, kf1, z);
      S0[c] = z;
      f32x4 z2 = {0.f, 0.f, 0.f, 0.f};
      z2 = mfma16(qf2, kf0, z2); z2 = mfma16(qf3, kf1, z2);
      T0[c] = z2;
    }
    __builtin_amdgcn_s_setprio(0);
    {
      float sh[5][4], si[5][4];
      #pragma unroll
      for (int s5 = 0; s5 < 5; s5++)
        #pragma unroll
        for (int r = 0; r < 4; r++) {
          sh[s5][r] = __shfl(Rm0[s5][r], srcl[r], 64);
          si[s5][r] = __shfl(Rn0[s5][r], srcl[r], 64);
        }
      #pragma unroll
      for (int c = 0; c < 4; c++)
        #pragma unroll
        for (int r = 0; r < 4; r++) {
          float s = S0[c][r] + (psel[r] ? sh[c][r] : sh[c+1][r]);
          unsigned bit;
          if (c == 0)      bit = (mw0[0][r].x >> lr) & 1u;
          else if (c == 1) bit = (mw0[0][r].x >> (16 + lr)) & 1u;
          else if (c == 2) bit = (mw0[0][r].y >> lr) & 1u;
          else             bit = (mw0[0][r].y >> (16 + lr)) & 1u;
          s = bit ? -1e9f : s;
          RP[w][g*4 + r][c*16 + lr] = f2bf(__builtin_amdgcn_exp2f(s));
        }
      pa000 = *(const bf16x8*)&RP[w][lr][g*8];
      pa001 = *(const bf16x8*)&RP[w][lr][32 + g*8];
      #pragma unroll
      for (int c = 0; c < 4; c++)
        #pragma unroll
        for (int r = 0; r < 4; r++) {
          float s = T0[c][r] + (psel[r] ? si[c][r] : si[c+1][r]);
          unsigned bit;
          if (c == 0)      bit = (mw1[0][r].x >> lr) & 1u;
          else if (c == 1) bit = (mw1[0][r].x >> (16 + lr)) & 1u;
          else if (c == 2) bit = (mw1[0][r].y >> lr) & 1u;
          else             bit = (mw1[0][r].y >> (16 + lr)) & 1u;
          s = bit ? -1e9f : s;
          RP[w][g*4 + r][c*16 + lr] = f2bf(__builtin_amdgcn_exp2f(s));
        }
      pa010 = *(const bf16x8*)&RP[w][lr][g*8];
      pa011 = *(const bf16x8*)&RP[w][lr][32 + g*8];
    }

    bf16x8 e1[5][2];
    #pragma unroll
    for (int j = 0; j < 5; j++) {
      const u16* ep = &Eb[(size_t)(rmin0 + 64 + j*16 + lr) * 64 + g*8];
      e1[j][0] = *(const bf16x8*)ep;
      e1[j][1] = *(const bf16x8*)(ep + 32);
    }
    f32x4 Rm1[5], Rn1[5];
    Rm1[0] = Rm0[4];
    Rn1[0] = Rn0[4];
    __builtin_amdgcn_s_setprio(1);
    #pragma unroll
    for (int j = 1; j < 5; j++) {
      f32x4 R = {0.f, 0.f, 0.f, 0.f};
      R = mfma16(qf0, e1[j][0], R);
      R = mfma16(qf1, e1[j][1], R);
      Rm1[j] = R;
      f32x4 R2 = {0.f, 0.f, 0.f, 0.f};
      R2 = mfma16(qf2, e1[j-1][0], R2);
      R2 = mfma16(qf3, e1[j-1][1], R2);
      Rn1[j] = R2;
    }
    __builtin_amdgcn_s_setprio(0);
    carry0 = Rm1[4];
    carry1 = Rn1[4];

    __builtin_amdgcn_sched_barrier(0);
    if (k0 + 128 < Tn) {
      kA = *(const int4*)(Kgs + (size_t)(k0 + 128) * 64);
      kB = *(const int4*)(Kgs + (size_t)(k0 + 192) * 64);
      vA = *(const int4*)(Vgs + k0 + 128);
      vB = *(const int4*)(Vgs + 32 * 1024 + k0 + 128);
    }
    __builtin_amdgcn_sched_barrier(0);

    f32x4 S1[4], T1[4];
    __builtin_amdgcn_s_setprio(1);
    #pragma unroll
    for (int c = 0; c < 4; c++) {
      int krow = 64 + c*16 + lr;
      bf16x8 kf0 = *(const bf16x8*)&KlF[krow*64 + kread];
      bf16x8 kf1 = *(const bf16x8*)&KlF[krow*64 + kread2];
      f32x4 z = {0.f, 0.f, 0.f, 0.f};
      z = mfma16(qf0, kf0, z); z = mfma16(qf1, kf1, z);
      S1[c] = z;
      f32x4 z2 = {0.f, 0.f, 0.f, 0.f};
      z2 = mfma16(qf2, kf0, z2); z2 = mfma16(qf3, kf1, z2);
      T1[c] = z2;
    }
    __builtin_amdgcn_s_setprio(0);
    {
      float sh[5][4], si[5][4];
      #pragma unroll
      for (int s5 = 0; s5 < 5; s5++)
        #pragma unroll
        for (int r = 0; r < 4; r++) {
          sh[s5][r] = __shfl(Rm1[s5][r], srcl[r], 64);
          si[s5][r] = __shfl(Rn1[s5][r], srcl[r], 64);
        }
      #pragma unroll
      for (int c = 0; c < 4; c++)
        #pragma unroll
        for (int r = 0; r < 4; r++) {
          float s = S1[c][r] + (psel[r] ? sh[c][r] : sh[c+1][r]);
          unsigned bit;
          if (c == 0)      bit = (mw0[1][r].x >> lr) & 1u;
          else if (c == 1) bit = (mw0[1][r].x >> (16 + lr)) & 1u;
          else if (c == 2) bit = (mw0[1][r].y >> lr) & 1u;
          else             bit = (mw0[1][r].y >> (16 + lr)) & 1u;
          s = bit ? -1e9f : s;
          RP[w][g*4 + r][c*16 + lr] = f2bf(__builtin_amdgcn_exp2f(s));
        }
      pa100 = *(const bf16x8*)&RP[w][lr][g*8];
      pa101 = *(const bf16x8*)&RP[w][lr][32 + g*8];
      #pragma unroll
      for (int c = 0; c < 4; c++)
        #pragma unroll
        for (int r = 0; r < 4; r++) {
          float s = T1[c][r] + (psel[r] ? si[c][r] : si[c+1][r]);
          unsigned bit;
          if (c == 0)      bit = (mw1[1][r].x >> lr) & 1u;
          else if (c == 1) bit = (mw1[1][r].x >> (16 + lr)) & 1u;
          else if (c == 2) bit = (mw1[1][r].y >> lr) & 1u;
          else             bit = (mw1[1][r].y >> (16 + lr)) & 1u;
          s = bit ? -1e9f : s;
          RP[w][g*4 + r][c*16 + lr] = f2bf(__builtin_amdgcn_exp2f(s));
        }
      pa110 = *(const bf16x8*)&RP[w][lr][g*8];
      pa111 = *(const bf16x8*)&RP[w][lr][32 + g*8];
    }

    __builtin_amdgcn_s_setprio(1);
    #pragma unroll
    for (int ct = 0; ct < 4; ct++) {
      bf16x8 vf0 = *(const bf16x8*)&Vt[ct*16 + lr][g*8];
      bf16x8 vf1 = *(const bf16x8*)&Vt[ct*16 + lr][32 + g*8];
      bf16x8 vf2 = *(const bf16x8*)&Vt[ct*16 + lr][64 + g*8];
      bf16x8 vf3 = *(const bf16x8*)&Vt[ct*16 + lr][96 + g*8];
      O[ct] = mfma16(pa000, vf0, O[ct]);
      O[ct] = mfma16(pa001, vf1, O[ct]);
      O[ct] = mfma16(pa100, vf2, O[ct]);
      O[ct] = mfma16(pa101, vf3, O[ct]);
      O[4+ct] = mfma16(pa010, vf0, O[4+ct]);
      O[4+ct] = mfma16(pa011, vf1, O[4+ct]);
      O[4+ct] = mfma16(pa110, vf2, O[4+ct]);
      O[4+ct] = mfma16(pa111, vf3, O[4+ct]);
    }
    Os0 = mfma16(pa000, one8.v, Os0);
    Os0 = mfma16(pa001, one8.v, Os0);
    Os0 = mfma16(pa100, one8.v, Os0);
    Os0 = mfma16(pa101, one8.v, Os0);
    Os1 = mfma16(pa010, one8.v, Os1);
    Os1 = mfma16(pa011, one8.v, Os1);
    Os1 = mfma16(pa110, one8.v, Os1);
    Os1 = mfma16(pa111, one8.v, Os1);
    __builtin_amdgcn_s_setprio(0);
  }
  float inv0[4], inv1[4];
  #pragma unroll
  for (int r = 0; r < 4; r++) { inv0[r] = 1.f / Os0[r]; inv1[r] = 1.f / Os1[r]; }
  #pragma unroll
  for (int ct = 0; ct < 4; ct++)
    #pragma unroll
    for (int r = 0; r < 4; r++) {
      int rowq = g*4 + r, col = ct*16 + lr;
      ctx[(size_t)(b*Tn + qw0 + rowq) * 1024 + h*64 + col] = f2bf(O[ct][r] * inv0[r]);
      ctx[(size_t)(b*Tn + qw0 + 16 + rowq) * 1024 + h*64 + col] = f2bf(O[4+ct][r] * inv1[r]);
    }
}

// ---------------- residual + LayerNorm ----------------
__global__ __launch_bounds__(256) void k_ln(const float* __restrict__ x, const u16* __restrict__ o,
                                            const float* __restrict__ gamma, const float* __restrict__ beta,
                                            float* __restrict__ out) {
  int m = blockIdx.x, tid = threadIdx.x;
  int w = tid >> 6, lane = tid & 63;
  const float* xr = x + (size_t)m * Dn;
  const u16* orow = o + (size_t)m * Dn;
  float4 xv = *(const float4*)&xr[tid*4];
  union { uint2 u; u16 s[4]; } ou;
  ou.u = *(const uint2*)&orow[tid*4];
  float y[4];
  y[0] = xv.x + bf2f(ou.s[0]);
  y[1] = xv.y + bf2f(ou.s[1]);
  y[2] = xv.z + bf2f(ou.s[2]);
  y[3] = xv.w + bf2f(ou.s[3]);
  float s = y[0]+y[1]+y[2]+y[3];
  float s2 = y[0]*y[0]+y[1]*y[1]+y[2]*y[2]+y[3]*y[3];
  #pragma unroll
  for (int off = 1; off < 64; off <<= 1) { s += __shfl_xor(s, off); s2 += __shfl_xor(s2, off); }
  __shared__ float red[8];
  if (lane == 0) { red[w] = s; red[4 + w] = s2; }
  __syncthreads();
  float Sa = red[0]+red[1]+red[2]+red[3];
  float Sb = red[4]+red[5]+red[6]+red[7];
  float mu = Sa * (1.f/1024.f);
  float var = Sb * (1.f/1024.f) - mu*mu;
  float rstd = rsqrtf(var + 1e-5f);
  #pragma unroll
  for (int i = 0; i < 4; i++) {
    int j = tid*4 + i;
    out[(size_t)m*Dn + j] = (y[i] - mu) * rstd * gamma[j] + beta[j];
  }
}

extern "C" void kernel_launch(void* const* d_in, const int* in_sizes, int n_in,
                              void* d_out, int out_size, void* d_ws, size_t ws_size,
                              hipStream_t stream) {
  const float* x    = (const float*)d_in[0];
  const float* ctxI = (const float*)d_in[1];
  const unsigned char* mask = (const unsigned char*)d_in[2];
  const float* lut  = (const float*)d_in[3];
  const float* Wq   = (const float*)d_in[4];
  const float* Wk   = (const float*)d_in[5];
  const float* Wv   = (const float*)d_in[6];
  const float* Wo   = (const float*)d_in[7];
  const float* bo   = (const float*)d_in[8];
  const float* gamma= (const float*)d_in[9];
  const float* beta = (const float*)d_in[10];
  float* out = (float*)d_out;

  u16* WqT  = (u16*)d_ws;
  u16* WkT  = WqT + 1048576;
  u16* WvT  = WkT + 1048576;   // contiguous with WkT -> fused KV GEMM reads [2048][1024]
  u16* WoT  = WvT + 1048576;
  u16* Ebf  = WoT + 1048576;
  u16* Qbf  = Ebf + 131072;
  u16* Kbf  = Qbf + 4194304;
  u16* Vbf  = Kbf + 4194304;   // holds V^T [B,H,DH,T]
  u16* ctxb = Vbf + 4194304;
  u16* obf  = ctxb + 4194304;
  unsigned long long* mbits = (unsigned long long*)(obf + 4194304); // 65536 words = 512 KB

  k_maskpack<<<2048, 256, 0, stream>>>(mask, mbits);
  k_convert<<<128, 256, 0, stream>>>(lut, Ebf, 131008);
  dim3 tb(32, 8), tg4(32, 32, 4);
  k_transpose_convert4<<<tg4, tb, 0, stream>>>(Wq, Wk, Wv, Wo, WqT, WkT, WvT, WoT);
  k_proj<<<768, 256, 0, stream>>>(x, ctxI, WqT, WkT, Qbf, Kbf, Vbf);
  k_attn<<<dim3(4, 16, 4), 512, 0, stream>>>(Qbf, Kbf, Vbf, Ebf, mbits, ctxb);
  k_gemm_bt<<<dim3(8, 32), 256, 0, stream>>>(ctxb, WoT, obf, bo);
  k_ln<<<4096, 256, 0, stream>>>(x, obf, gamma, beta, out);
}